// Round 2
// baseline (201.513 us; speedup 1.0000x reference)
//
#include <hip/hip_runtime.h>

#define B_   32
#define NGT  50
#define NA_  8400
#define IMG_ 640

// ws layout (floats):
//  [0] sum_iou   [1] sum_mask   [2] sum_imask
//  [4+b]  obj_sum[b]   (32)
//  [36+b] cls_sum[b]   (32)
//  [68+b] fg_sum[b]    (32)

__device__ __forceinline__ float softplusf(float x) {
    // jax.nn.softplus == logaddexp(x, 0) == max(x,0) + log1p(exp(-|x|))
    return fmaxf(x, 0.0f) + log1pf(expf(-fabsf(x)));
}

__global__ void __launch_bounds__(256) yolox_main(
    const float* __restrict__ targets,          // [B,50,5]
    const float* __restrict__ output,           // [B,NA,7]
    const int* __restrict__ fg_mask,            // [B,NA] (bool widened to int32)
    const int* __restrict__ matched,            // [B,NA]
    const float* __restrict__ pred_ious,        // [B,NA]
    const float* __restrict__ masks,            // [B,640,640,2]
    float* __restrict__ ws)
{
    const int b = blockIdx.y;
    const int a = blockIdx.x * blockDim.x + threadIdx.x;

    __shared__ float gt[NGT * 4];
    for (int i = threadIdx.x; i < NGT * 4; i += blockDim.x) {
        int g = i >> 2, k = i & 3;
        gt[i] = targets[b * (NGT * 5) + g * 5 + 1 + k];
    }
    __syncthreads();

    float iou_p = 0.f, mask_p = 0.f, imask_p = 0.f, obj_p = 0.f, cls_p = 0.f, fg_p = 0.f;

    if (a < NA_) {
        const float* o = output + ((long)b * NA_ + a) * 7;
        float px = o[0], py = o[1], pw = o[2], ph = o[3];
        float lm = o[4], lo = o[5], lc = o[6];

        int   gi  = matched[b * NA_ + a];
        float gx = gt[gi*4+0], gy = gt[gi*4+1], gw = gt[gi*4+2], gh = gt[gi*4+3];
        float fgf = (fg_mask[b * NA_ + a] != 0) ? 1.0f : 0.0f;

        // ---- IOU loss (YOLOX iou, 1 - iou^2), masked by fg ----
        float tlx = fmaxf(px - pw*0.5f, gx - gw*0.5f);
        float tly = fmaxf(py - ph*0.5f, gy - gh*0.5f);
        float brx = fminf(px + pw*0.5f, gx + gw*0.5f);
        float bry = fminf(py + ph*0.5f, gy + gh*0.5f);
        float area_p = pw * ph;
        float area_g = gw * gh;
        float en = (tlx < brx && tly < bry) ? 1.0f : 0.0f;
        float area_i = (brx - tlx) * (bry - tly) * en;
        float iou = area_i / (area_p + area_g - area_i + 1e-16f);
        iou_p = (1.0f - iou * iou) * fgf;

        // ---- obj BCE over ALL anchors, label = fgf ----
        obj_p = softplusf(lo) - lo * fgf;

        // ---- cls BCE, label = pred_ious, masked by fg ----
        float pi = pred_ious[b * NA_ + a];
        cls_p = (softplusf(lc) - lc * pi) * fgf;

        // ---- mask BCE: nearest-resize pixel-center sample ----
        int y, x;
        if (a < 6400)      { int p = a;        y = (p / 80) * 8  + 4;  x = (p % 80) * 8  + 4;  }
        else if (a < 8000) { int p = a - 6400; y = (p / 40) * 16 + 8;  x = (p % 40) * 16 + 8;  }
        else               { int p = a - 8000; y = (p / 20) * 32 + 16; x = (p % 20) * 32 + 16; }
        const float2 mv = *reinterpret_cast<const float2*>(
            masks + (((long)b * IMG_ + y) * IMG_ + x) * 2);
        float bm = mv.x, tm = mv.y;
        float imask = (bm + tm) > 0.0f ? 1.0f : 0.0f;
        mask_p  = (softplusf(lm) - lm * tm) * imask;
        imask_p = imask;
        fg_p    = fgf;
    }

    // ---- block reduction: 6 values, wave64 shuffle then LDS across waves ----
    #pragma unroll
    for (int off = 32; off > 0; off >>= 1) {
        iou_p   += __shfl_down(iou_p,   off);
        mask_p  += __shfl_down(mask_p,  off);
        imask_p += __shfl_down(imask_p, off);
        obj_p   += __shfl_down(obj_p,   off);
        cls_p   += __shfl_down(cls_p,   off);
        fg_p    += __shfl_down(fg_p,    off);
    }

    __shared__ float part[4][6];
    int wave = threadIdx.x >> 6;
    int lane = threadIdx.x & 63;
    if (lane == 0) {
        part[wave][0] = iou_p;   part[wave][1] = mask_p; part[wave][2] = imask_p;
        part[wave][3] = obj_p;   part[wave][4] = cls_p;  part[wave][5] = fg_p;
    }
    __syncthreads();
    if (threadIdx.x == 0) {
        float s0 = 0.f, s1 = 0.f, s2 = 0.f, s3 = 0.f, s4 = 0.f, s5 = 0.f;
        #pragma unroll
        for (int w = 0; w < 4; ++w) {
            s0 += part[w][0]; s1 += part[w][1]; s2 += part[w][2];
            s3 += part[w][3]; s4 += part[w][4]; s5 += part[w][5];
        }
        atomicAdd(&ws[0], s0);
        atomicAdd(&ws[1], s1);
        atomicAdd(&ws[2], s2);
        atomicAdd(&ws[4  + b], s3);
        atomicAdd(&ws[36 + b], s4);
        atomicAdd(&ws[68 + b], s5);
    }
}

__global__ void __launch_bounds__(64) yolox_final(
    const float* __restrict__ targets,
    const float* __restrict__ ws,
    float* __restrict__ out)
{
    int t = threadIdx.x;  // 64 lanes, one wave
    float fg_b = 0.f, ngt_b = 0.f, obj_b = 0.f, cls_b = 0.f;
    if (t < B_) {
        int cnt = 0;
        for (int g = 0; g < NGT; ++g)
            cnt += (targets[t * (NGT * 5) + g * 5] > 0.0f) ? 1 : 0;
        ngt_b = (float)cnt;
        obj_b = ws[4 + t];
        cls_b = ws[36 + t];
        fg_b  = ws[68 + t];
        float ll = (cnt > 0) ? (obj_b + cls_b) / fmaxf(fg_b, 1.0f) : -1.0f;
        out[5 + t] = ll;  // loss_list[t]
    }
    float fg_tot = fg_b, ngt_tot = ngt_b, obj_tot = obj_b, cls_tot = cls_b;
    #pragma unroll
    for (int off = 32; off > 0; off >>= 1) {
        fg_tot  += __shfl_down(fg_tot,  off);
        ngt_tot += __shfl_down(ngt_tot, off);
        obj_tot += __shfl_down(obj_tot, off);
        cls_tot += __shfl_down(cls_tot, off);
    }
    if (t == 0) {
        float num_f = fmaxf(fg_tot, 1.0f);
        float num_g = fmaxf(ngt_tot, 1.0f);
        float num_m = fmaxf(ws[2], 1.0f);
        float iou_loss  = 5.0f * ws[0] / num_f;
        float obj_loss  = obj_tot / num_f;
        float cls_loss  = cls_tot / num_f;
        float mask_loss = ws[1] / num_m * 2.0f;
        out[0] = iou_loss + obj_loss + cls_loss + mask_loss;
        out[1] = iou_loss;
        out[2] = obj_loss;
        out[3] = cls_loss;
        out[4] = mask_loss;
        out[37] = num_f / num_g;
    }
}

extern "C" void kernel_launch(void* const* d_in, const int* in_sizes, int n_in,
                              void* d_out, int out_size, void* d_ws, size_t ws_size,
                              hipStream_t stream) {
    const float* targets = (const float*)d_in[0];
    const float* output  = (const float*)d_in[1];
    const int*   fg      = (const int*)d_in[2];
    const int*   matched = (const int*)d_in[3];
    const float* pious   = (const float*)d_in[4];
    const float* masks   = (const float*)d_in[5];
    float* out = (float*)d_out;
    float* ws  = (float*)d_ws;

    hipMemsetAsync(ws, 0, 128 * sizeof(float), stream);

    dim3 grid((NA_ + 255) / 256, B_);
    yolox_main<<<grid, 256, 0, stream>>>(targets, output, fg, matched, pious, masks, ws);
    yolox_final<<<1, 64, 0, stream>>>(targets, ws, out);
}

// Round 3
// 155.907 us; speedup vs baseline: 1.2925x; 1.2925x over previous
//
#include <hip/hip_runtime.h>

#define B_   32
#define NGT  50
#define NA_  8400
#define IMG_ 640
#define NCHUNK 16   // main-kernel blocks per image

// ws layout: partials[b][chunk][8] floats; q: 0=iou 1=mask 2=imask 3=obj 4=cls 5=fg
// Every slot is written unconditionally by its block -> no zero-init needed.

__device__ __forceinline__ float softplusf(float x) {
    // jax.nn.softplus == max(x,0) + log1p(exp(-|x|))
    return fmaxf(x, 0.0f) + log1pf(expf(-fabsf(x)));
}

__global__ void __launch_bounds__(256) yolox_main(
    const float* __restrict__ targets,          // [B,50,5]
    const float* __restrict__ output,           // [B,NA,7]
    const int* __restrict__ fg_mask,            // [B,NA] (bool widened to int32)
    const int* __restrict__ matched,            // [B,NA]
    const float* __restrict__ pred_ious,        // [B,NA]
    const float* __restrict__ masks,            // [B,640,640,2]
    float* __restrict__ ws)
{
    const int b  = blockIdx.y;
    const int cx = blockIdx.x;

    __shared__ float gt[NGT * 4];
    for (int i = threadIdx.x; i < NGT * 4; i += blockDim.x) {
        int g = i >> 2, k = i & 3;
        gt[i] = targets[b * (NGT * 5) + g * 5 + 1 + k];
    }
    __syncthreads();

    float iou_p = 0.f, mask_p = 0.f, imask_p = 0.f, obj_p = 0.f, cls_p = 0.f, fg_p = 0.f;

    for (int a = cx * 256 + threadIdx.x; a < NA_; a += NCHUNK * 256) {
        const float* o = output + ((long)b * NA_ + a) * 7;
        float px = o[0], py = o[1], pw = o[2], ph = o[3];
        float lm = o[4], lo = o[5], lc = o[6];

        int   gi  = matched[b * NA_ + a];
        float gx = gt[gi*4+0], gy = gt[gi*4+1], gw = gt[gi*4+2], gh = gt[gi*4+3];
        float fgf = (fg_mask[b * NA_ + a] != 0) ? 1.0f : 0.0f;

        // ---- IOU loss (1 - iou^2), masked by fg ----
        float tlx = fmaxf(px - pw*0.5f, gx - gw*0.5f);
        float tly = fmaxf(py - ph*0.5f, gy - gh*0.5f);
        float brx = fminf(px + pw*0.5f, gx + gw*0.5f);
        float bry = fminf(py + ph*0.5f, gy + gh*0.5f);
        float area_p = pw * ph;
        float area_g = gw * gh;
        float en = (tlx < brx && tly < bry) ? 1.0f : 0.0f;
        float area_i = (brx - tlx) * (bry - tly) * en;
        float iou = area_i / (area_p + area_g - area_i + 1e-16f);
        iou_p += (1.0f - iou * iou) * fgf;

        // ---- obj BCE over ALL anchors ----
        obj_p += softplusf(lo) - lo * fgf;

        // ---- cls BCE, label = pred_ious, masked by fg ----
        float pi = pred_ious[b * NA_ + a];
        cls_p += (softplusf(lc) - lc * pi) * fgf;

        // ---- mask BCE: nearest-resize pixel-center sample ----
        int y, x;
        if (a < 6400)      { int p = a;        y = (p / 80) * 8  + 4;  x = (p % 80) * 8  + 4;  }
        else if (a < 8000) { int p = a - 6400; y = (p / 40) * 16 + 8;  x = (p % 40) * 16 + 8;  }
        else               { int p = a - 8000; y = (p / 20) * 32 + 16; x = (p % 20) * 32 + 16; }
        const float2 mv = *reinterpret_cast<const float2*>(
            masks + (((long)b * IMG_ + y) * IMG_ + x) * 2);
        float bm = mv.x, tm = mv.y;
        float imask = (bm + tm) > 0.0f ? 1.0f : 0.0f;
        mask_p  += (softplusf(lm) - lm * tm) * imask;
        imask_p += imask;
        fg_p    += fgf;
    }

    // ---- block reduction: wave shuffle then LDS across 4 waves ----
    #pragma unroll
    for (int off = 32; off > 0; off >>= 1) {
        iou_p   += __shfl_down(iou_p,   off);
        mask_p  += __shfl_down(mask_p,  off);
        imask_p += __shfl_down(imask_p, off);
        obj_p   += __shfl_down(obj_p,   off);
        cls_p   += __shfl_down(cls_p,   off);
        fg_p    += __shfl_down(fg_p,    off);
    }

    __shared__ float part[4][6];
    int wave = threadIdx.x >> 6;
    int lane = threadIdx.x & 63;
    if (lane == 0) {
        part[wave][0] = iou_p; part[wave][1] = mask_p; part[wave][2] = imask_p;
        part[wave][3] = obj_p; part[wave][4] = cls_p;  part[wave][5] = fg_p;
    }
    __syncthreads();
    if (threadIdx.x == 0) {
        float s[6];
        #pragma unroll
        for (int q = 0; q < 6; ++q)
            s[q] = part[0][q] + part[1][q] + part[2][q] + part[3][q];
        float* dst = ws + ((long)b * NCHUNK + cx) * 8;
        #pragma unroll
        for (int q = 0; q < 6; ++q) dst[q] = s[q];
    }
}

__global__ void __launch_bounds__(512) yolox_final(
    const float* __restrict__ targets,
    const float* __restrict__ ws,
    float* __restrict__ out)
{
    const int t = threadIdx.x;   // 512 threads: 16-lane group per image
    const int b = t >> 4;        // image 0..31
    const int i = t & 15;        // chunk

    const float* p = ws + ((long)b * NCHUNK + i) * 8;
    float iou = p[0], msk = p[1], ims = p[2], obj = p[3], cls = p[4], fg = p[5];

    // per-image GT count: flags at targets[b*250 + g*5]
    float ngt = 0.f;
    for (int g = i; g < NGT; g += 16)
        ngt += (targets[b * (NGT * 5) + g * 5] > 0.0f) ? 1.0f : 0.0f;

    // reduce within each 16-lane group
    #pragma unroll
    for (int off = 8; off > 0; off >>= 1) {
        iou += __shfl_down(iou, off, 16);
        msk += __shfl_down(msk, off, 16);
        ims += __shfl_down(ims, off, 16);
        obj += __shfl_down(obj, off, 16);
        cls += __shfl_down(cls, off, 16);
        fg  += __shfl_down(fg,  off, 16);
        ngt += __shfl_down(ngt, off, 16);
    }

    __shared__ float sm[32][8];
    if (i == 0) {
        out[5 + b] = (ngt > 0.f) ? (obj + cls) / fmaxf(fg, 1.0f) : -1.0f;
        sm[b][0] = iou; sm[b][1] = msk; sm[b][2] = ims;
        sm[b][3] = obj; sm[b][4] = cls; sm[b][5] = fg; sm[b][6] = ngt;
    }
    __syncthreads();

    if (t < 32) {
        float v0 = sm[t][0], v1 = sm[t][1], v2 = sm[t][2];
        float v3 = sm[t][3], v4 = sm[t][4], v5 = sm[t][5], v6 = sm[t][6];
        #pragma unroll
        for (int off = 16; off > 0; off >>= 1) {
            v0 += __shfl_down(v0, off, 32);
            v1 += __shfl_down(v1, off, 32);
            v2 += __shfl_down(v2, off, 32);
            v3 += __shfl_down(v3, off, 32);
            v4 += __shfl_down(v4, off, 32);
            v5 += __shfl_down(v5, off, 32);
            v6 += __shfl_down(v6, off, 32);
        }
        if (t == 0) {
            float num_f = fmaxf(v5, 1.0f);
            float num_g = fmaxf(v6, 1.0f);
            float num_m = fmaxf(v2, 1.0f);
            float iou_loss  = 5.0f * v0 / num_f;
            float obj_loss  = v3 / num_f;
            float cls_loss  = v4 / num_f;
            float mask_loss = v1 / num_m * 2.0f;
            out[0] = iou_loss + obj_loss + cls_loss + mask_loss;
            out[1] = iou_loss;
            out[2] = obj_loss;
            out[3] = cls_loss;
            out[4] = mask_loss;
            out[37] = num_f / num_g;
        }
    }
}

extern "C" void kernel_launch(void* const* d_in, const int* in_sizes, int n_in,
                              void* d_out, int out_size, void* d_ws, size_t ws_size,
                              hipStream_t stream) {
    const float* targets = (const float*)d_in[0];
    const float* output  = (const float*)d_in[1];
    const int*   fg      = (const int*)d_in[2];
    const int*   matched = (const int*)d_in[3];
    const float* pious   = (const float*)d_in[4];
    const float* masks   = (const float*)d_in[5];
    float* out = (float*)d_out;
    float* ws  = (float*)d_ws;

    dim3 grid(NCHUNK, B_);
    yolox_main<<<grid, 256, 0, stream>>>(targets, output, fg, matched, pious, masks, ws);
    yolox_final<<<1, 512, 0, stream>>>(targets, ws, out);
}